// Round 1
// 106.751 us; speedup vs baseline: 1.0198x; 1.0198x over previous
//
#include <hip/hip_runtime.h>
#include <type_traits>

typedef unsigned short u16;
typedef __attribute__((ext_vector_type(8))) short short8;
typedef __attribute__((ext_vector_type(4))) float floatx4;

__device__ __forceinline__ u16 f2u(float f) {
  unsigned int x = __float_as_uint(f);
  x += 0x7fff + ((x >> 16) & 1);  // RNE to bf16
  return (u16)(x >> 16);
}

__device__ __forceinline__ void async16(const void* g, void* l) {
  __builtin_amdgcn_global_load_lds(
      (const __attribute__((address_space(1))) unsigned int*)g,
      (__attribute__((address_space(3))) unsigned int*)l, 16, 0, 0);
}

// Transpose+cast, one dispatch, two jobs decoded from blockIdx.x:
//  b < 1024 : U[2048][2048] fp32 -> Ut (transposed bf16) + Ubf (straight bf16)
//  b < 1152 : x[2048][256]  fp32 -> xT[256][2048] bf16
__global__ __launch_bounds__(256) void prep_kernel(
    const float* __restrict__ U, const float* __restrict__ x,
    u16* __restrict__ Ut, u16* __restrict__ Ubf, u16* __restrict__ xT,
    int N, int F) {
  __shared__ __attribute__((aligned(16))) float tile[64][65];
  int bb = blockIdx.x;
  int t = threadIdx.x;

  const float* in;
  u16 *outT, *outC;
  int R, C, c0, r0;
  if (bb < 1024) {  // U job
    in = U; outT = Ut; outC = Ubf; R = N; C = N;
    c0 = (bb & 31) * 64; r0 = (bb >> 5) * 64;
  } else {  // x job
    int b2 = bb - 1024;
    in = x; outT = xT; outC = nullptr; R = N; C = F;
    c0 = (b2 & 3) * 64; r0 = (b2 >> 2) * 64;
  }

#pragma unroll
  for (int p = 0; p < 4; ++p) {
    int e = p * 256 + t;
    int row = e >> 4, col = (e & 15) * 4;
    float4 v = *(const float4*)(in + (size_t)(r0 + row) * C + c0 + col);
    tile[row][col] = v.x;
    tile[row][col + 1] = v.y;
    tile[row][col + 2] = v.z;
    tile[row][col + 3] = v.w;
    if (outC) {
      union { uint2 u; u16 s[4]; } pk;
      pk.s[0] = f2u(v.x); pk.s[1] = f2u(v.y);
      pk.s[2] = f2u(v.z); pk.s[3] = f2u(v.w);
      *(uint2*)(outC + (size_t)(r0 + row) * C + c0 + col) = pk.u;
    }
  }
  __syncthreads();
#pragma unroll
  for (int p = 0; p < 2; ++p) {
    int e = p * 256 + t;
    int orow = e >> 3, oc = (e & 7) * 8;
    union { uint4 v; u16 s[8]; } tmp;
#pragma unroll
    for (int i = 0; i < 8; ++i) tmp.s[i] = f2u(tile[oc + i][orow]);
    *(uint4*)(outT + (size_t)(c0 + orow) * R + r0 + oc) = tmp.v;
  }
}

// Direct TN GEMM: C[m][col] = sum_k A[m][k]*B[col][k]
// BM=BN=32; 4 waves, each wave computes the FULL 32x32 tile (2x2 accs of
// 16x16) over a QUARTER of K (wave w takes k32-subtiles {2w,2w+1} of each
// macro) -> 2x fewer LDS reads/MFMA than 1-acc-per-wave; fp32 cross-wave
// reduction in LDS at the end.
// LDS k-chunk XOR swizzle (chunk ^= (row>>1)&3): applied on the pre-swizzled
// GLOBAL source (global_load_lds dest must stay linear) and on the read
// address. Kills the 8-way ds_read_b128 bank conflict of the row*64B layout
// (consecutive 8 lanes now cover all 8 16B-slot positions).
// Macro BK=256 (8 k32-subtiles), double-buffered LDS, ONE barrier per macro.
// 1-D grid of 512 with XCD-aware decode (xcd = b % 8 round-robin):
//  WIDE_N  (GEMM1, 8 m x 64 n): m=(b>>3)&7,        n=(b&7)*8+(b>>6)
//  !WIDE_N (GEMM2, 64 m x 8 n): m=(b&7)*8+(b>>6),  n=(b>>3)&7
// SCALE_D: *= d(col) inline from lam/pa/pb/pc.  RESIDUAL: += alpha*resid.
template <bool WIDE_N, bool SCALE_D, bool RESIDUAL, typename CT>
__global__ __launch_bounds__(256) void gemm32(
    const u16* __restrict__ A, const u16* __restrict__ B, CT* __restrict__ C,
    int M, int NN, int K, const float* __restrict__ lam,
    const float* __restrict__ pa, const float* __restrict__ pb,
    const float* __restrict__ pc, const float* __restrict__ resid,
    const float* __restrict__ alpha_p) {
  __shared__ __attribute__((aligned(16))) u16 lA[2 * 8192];  // 32 KB
  __shared__ __attribute__((aligned(16))) u16 lB[2 * 8192];  // 32 KB
  const int b = blockIdx.x;
  int m0, n0;
  if (WIDE_N) {
    m0 = ((b >> 3) & 7) * 32;
    n0 = ((b & 7) * 8 + (b >> 6)) * 32;
  } else {
    m0 = ((b & 7) * 8 + (b >> 6)) * 32;
    n0 = ((b >> 3) & 7) * 32;
  }
  const int t = threadIdx.x;
  const int wave = t >> 6, lane = t & 63;
  const int q = lane >> 4, l15 = lane & 15;

  // Staging: thread -> (row, k-chunk); pre-swizzle the global k-chunk so the
  // linear LDS destination ends up XOR-swizzled: slot c holds chunk c^s(row).
  const int within = t & 127, st0 = t >> 7;  // st0 in {0,1}
  const int srow = within >> 2;
  const int schunk = (within & 3) ^ ((srow >> 1) & 3);
  const u16* gA = A + (size_t)(m0 + srow) * K + schunk * 8;
  const u16* gB = B + (size_t)(n0 + srow) * K + schunk * 8;
  char* lAc = (char*)lA;
  char* lBc = (char*)lB;

  const int NM = K >> 8;  // macro-iters (K/256)

  auto issue = [&](int i, int buf) {
    int k0 = i * 256;
#pragma unroll
    for (int p = 0; p < 4; ++p) {
      int st = 2 * p + st0;
      async16(gA + k0 + st * 32, lAc + buf * 16384 + p * 4096 + t * 16);
      async16(gB + k0 + st * 32, lBc + buf * 16384 + p * 4096 + t * 16);
    }
  };

  floatx4 acc[2][2];
#pragma unroll
  for (int m = 0; m < 2; ++m)
#pragma unroll
    for (int n = 0; n < 2; ++n) acc[m][n] = (floatx4){0.f, 0.f, 0.f, 0.f};

  // Read-side swizzled chunk offset (row = m*16+l15; bits 1..2 of row = l15's)
  const int ksw = (q ^ ((l15 >> 1) & 3)) * 8;

  issue(0, 0);
  for (int i = 0; i < NM; ++i) {
    const int buf = i & 1;
    __syncthreads();  // drains buf's prefetch; all waves done with buf^1
    if (i + 1 < NM) issue(i + 1, buf ^ 1);
    const u16* lAb = lA + buf * 8192;  // u16 units
    const u16* lBb = lB + buf * 8192;
#pragma unroll
    for (int ss = 0; ss < 2; ++ss) {
      const int st = 2 * wave + ss;  // this wave's k32-subtiles of the macro
      const u16* As = lAb + st * 1024;
      const u16* Bs = lBb + st * 1024;
      short8 af[2], bf[2];
#pragma unroll
      for (int m = 0; m < 2; ++m)
        af[m] = *(const short8*)&As[(m * 16 + l15) * 32 + ksw];
#pragma unroll
      for (int n = 0; n < 2; ++n)
        bf[n] = *(const short8*)&Bs[(n * 16 + l15) * 32 + ksw];
#pragma unroll
      for (int m = 0; m < 2; ++m)
#pragma unroll
        for (int n = 0; n < 2; ++n)
          acc[m][n] =
              __builtin_amdgcn_mfma_f32_16x16x32_bf16(af[m], bf[n], acc[m][n], 0, 0, 0);
    }
  }

  // Cross-wave K-reduction through LDS (reuse lA: need 16 KB, have 32 KB).
  __syncthreads();
  float* red = (float*)lA;
  // C/D layout: col=lane&15, row=(lane>>4)*4+reg  [m89/m91]
#pragma unroll
  for (int m = 0; m < 2; ++m)
#pragma unroll
    for (int n = 0; n < 2; ++n)
#pragma unroll
      for (int r = 0; r < 4; ++r)
        red[wave * 1024 + (m * 16 + q * 4 + r) * 32 + n * 16 + l15] = acc[m][n][r];
  __syncthreads();

  // Each thread finalizes 4 output elems; col fixed per thread (e=t+256p).
  const int col = t & 31;
  float ds = 1.f;
  if (SCALE_D) {
    const int ac = n0 + col;
    float lv = lam[(size_t)ac * NN + ac];
    float dacc = 0.f;
#pragma unroll
    for (int i = 0; i < 4; ++i) {
      float ai = pa[i], bi = pb[i], ci = pc[i];
      float rep = (ai - lv) * (lv - bi);
      rep = rep > 0.f ? rep : 0.f;
      dacc += ci * 4.f / ((ai - bi) * (ai - bi)) * rep;
    }
    ds = dacc;
  }
  float alpha = 0.f;
  if (RESIDUAL) alpha = alpha_p[0];
#pragma unroll
  for (int p = 0; p < 4; ++p) {
    const int row = (t >> 5) + p * 8;
    const int e = row * 32 + col;
    float v = red[e] + red[1024 + e] + red[2048 + e] + red[3072 + e];
    if (SCALE_D) v *= ds;
    size_t idx = (size_t)(m0 + row) * NN + (n0 + col);
    if (RESIDUAL) v += alpha * resid[idx];
    if constexpr (std::is_same<CT, u16>::value)
      C[idx] = f2u(v);
    else
      C[idx] = v;
  }
}

extern "C" void kernel_launch(void* const* d_in, const int* in_sizes, int n_in,
                              void* d_out, int out_size, void* d_ws,
                              size_t ws_size, hipStream_t stream) {
  const int N = 2048, F = 256;
  const float* x = (const float*)d_in[0];     // [N][F] fp32
  const float* lam = (const float*)d_in[1];   // [N][N] fp32 (diag)
  const float* U = (const float*)d_in[2];     // [N][N] fp32
  const float* a = (const float*)d_in[3];
  const float* b = (const float*)d_in[4];
  const float* c = (const float*)d_in[5];
  const float* alpha = (const float*)d_in[6];
  // d_in[7] = edge_index: unused by the reference math

  char* ws = (char*)d_ws;
  u16* xT = (u16*)ws;                          // [F][N] bf16 1 MB
  u16* Ut = (u16*)(ws + (1 << 20));            // [N][N] bf16 (U^T) 8 MB
  u16* Ubf = (u16*)(ws + (9 << 20));           // [N][N] bf16 8 MB
  u16* zT = (u16*)(ws + (17 << 20));           // [F][N] bf16 1 MB

  // prep: Ut + Ubf + xT in one dispatch
  prep_kernel<<<1152, 256, 0, stream>>>(U, x, Ut, Ubf, xT, N, F);
  // GEMM1: zT[f][j] = d[j] * sum_n xT[f][n]*Ut[j][n]   (bf16 out)
  gemm32<true, true, false, u16><<<512, 256, 0, stream>>>(
      xT, Ut, zT, F, N, N, lam, a, b, c, nullptr, nullptr);
  // GEMM2: out[n][f] = alpha*x[n][f] + sum_j Ubf[n][j]*zT[f][j]  (fp32 out)
  gemm32<false, false, true, float><<<512, 256, 0, stream>>>(
      Ubf, zT, (float*)d_out, N, F, N, nullptr, nullptr, nullptr, nullptr,
      x, alpha);
}